// Round 11
// baseline (723.097 us; speedup 1.0000x reference)
//
#include <hip/hip_runtime.h>

// LSTM T=2048,B=2048,H=32,I=1,O=1 fused in ONE kernel.
// R11 = R10 (712us champion) with the serial tail trimmed:
//  - Output projection (DPP tree + store) of h_{t-1} runs at the TOP of
//    step t, from the previous h still in registers: independent of the
//    hq LDS reads and the current dot -> schedules into the lgkm wait +
//    dot-issue phase instead of extending the post-activation tail.
//    First step peeled (no store), final projection peeled after the loop.
//  - c maintained pre-scaled (c2 = 2*log2e*c) via gv2 = 2L2E - 4L2E*rcp(..):
//    removes the dependent mul before tanh(c)'s exp2 (chain -1 dep).
// Budget model (explains all rounds): issue ~516 cyc/step (dot 256, trans
// at 1/8 wave-rate 160, misc 100) + act-chain ~160 + LDS turnaround ~120.
// Shape: wave64 = 2 batch elements in lockstep halves; lane owns unit
// j=l&31 of its half's element, all 4 gates; f32 throughout.

namespace {
constexpr int T_ = 2048;
constexpr int B_ = 2048;
constexpr int H_ = 32;
constexpr int WPB = 4;              // waves per block; each wave = 2 elements
constexpr int EPB = WPB * 2;        // batch elements per block
constexpr int CHUNK = 32;           // timesteps of x held in one VGPR
constexpr int NCH = T_ / CHUNK;     // 64
constexpr int OUTS = T_ * B_;       // floats of outs [T,B,1]
constexpr float L2E = 1.442695040888963f;  // log2(e)

typedef float v2f __attribute__((ext_vector_type(2)));
typedef float v4f __attribute__((ext_vector_type(4)));

__device__ __forceinline__ float rcp_(float v){ return __builtin_amdgcn_rcpf(v); }
__device__ __forceinline__ float ex2_(float v){ return __builtin_amdgcn_exp2f(v); }

template <int CTRL, int RM, int BM, bool BC>
__device__ __forceinline__ float dpp_add(float acc, float src) {
    int mv = __builtin_amdgcn_update_dpp(0, __builtin_bit_cast(int, src),
                                         CTRL, RM, BM, BC);
    return acc + __builtin_bit_cast(float, mv);
}
// Sum within each 32-lane half; result in lane 31 (half0) / lane 63 (half1).
__device__ __forceinline__ float half_sum32(float v) {
    v = dpp_add<0x111, 0xF, 0xF, true >(v, v);  // row_shr:1
    v = dpp_add<0x112, 0xF, 0xF, true >(v, v);  // row_shr:2
    v = dpp_add<0x114, 0xF, 0xF, true >(v, v);  // row_shr:4
    v = dpp_add<0x118, 0xF, 0xF, true >(v, v);  // row_shr:8
    v = dpp_add<0x142, 0xA, 0xF, false>(v, v);  // row_bcast:15 -> rows 1,3
    return v;
}
} // namespace

__global__ __launch_bounds__(256, 1)
__attribute__((amdgpu_num_vgpr(256)))
void lstm_fused11(
    const float* __restrict__ x,      // [T,B,1]
    const float* __restrict__ W_ih,   // [4H,1]
    const float* __restrict__ W_hh,   // [4H,H]
    const float* __restrict__ b_ih,   // [4H]
    const float* __restrict__ b_hh,   // [4H]
    const float* __restrict__ W_out,  // [1,H]
    const float* __restrict__ b_out,  // [1]
    float* __restrict__ out)          // outs | hT | cT
{
    const int l  = threadIdx.x & 63;
    const int wv = threadIdx.x >> 6;
    const int j  = l & 31;            // hidden unit
    const int p  = l >> 5;            // element half within wave
    const int e  = blockIdx.x * EPB + wv * 2 + p;

    __shared__ __align__(16) float hbuf[WPB][2][H_];

    const float sI = -L2E, sF = -L2E, sG = 2.0f * L2E, sO = -L2E;

    // W_hh rows j (i), j+H (f), j+2H (g), j+3H (o); packed k-pairs, pre-scaled
    // so activations need no dependent mul before exp2.
    v2f wi[H_/2], wf[H_/2], wg[H_/2], wo[H_/2];
#pragma unroll
    for (int k2 = 0; k2 < H_/2; ++k2) {
        const float* ri = W_hh + (0*H_ + j) * H_;
        const float* rf = W_hh + (1*H_ + j) * H_;
        const float* rg = W_hh + (2*H_ + j) * H_;
        const float* ro = W_hh + (3*H_ + j) * H_;
        wi[k2] = (v2f){ ri[2*k2] * sI, ri[2*k2+1] * sI };
        wf[k2] = (v2f){ rf[2*k2] * sF, rf[2*k2+1] * sF };
        wg[k2] = (v2f){ rg[2*k2] * sG, rg[2*k2+1] * sG };
        wo[k2] = (v2f){ ro[2*k2] * sO, ro[2*k2+1] * sO };
    }
#pragma unroll
    for (int k2 = 0; k2 < H_/2; ++k2) {       // init-time pins
        __asm__ __volatile__("" : "+v"(wi[k2]));
        __asm__ __volatile__("" : "+v"(wf[k2]));
        __asm__ __volatile__("" : "+v"(wg[k2]));
        __asm__ __volatile__("" : "+v"(wo[k2]));
    }

    const float wxi = W_ih[0*H_+j] * sI, wxf = W_ih[1*H_+j] * sF;
    const float wxg = W_ih[2*H_+j] * sG, wxo = W_ih[3*H_+j] * sO;
    const float bi  = (b_ih[0*H_+j] + b_hh[0*H_+j]) * sI;
    const float bf  = (b_ih[1*H_+j] + b_hh[1*H_+j]) * sF;
    const float bg  = (b_ih[2*H_+j] + b_hh[2*H_+j]) * sG;
    const float bo_ = (b_ih[3*H_+j] + b_hh[3*H_+j]) * sO;
    const float wout = W_out[j];
    const float bout = b_out[0];

    float c2 = 0.0f, h = 0.0f;           // c2 = 2*L2E * c
    hbuf[wv][p][j] = 0.0f;               // h0 = 0
    __asm__ __volatile__("" ::: "memory");
    v4f hq[H_/4];
#pragma unroll
    for (int q = 0; q < H_/4; ++q)       // h_0 fragments for step 0
        hq[q] = ((const v4f*)&hbuf[wv][p][0])[q];

    float xcur = x[j * B_ + e];          // chunk 0: lane j holds t=j
    int outPr = e;                       // store slot for proj(h_{t-1})

    // One recurrent step. doStore=false only for the very first step
    // (there is no h_{t-1} to project yet).
    auto body = [&](int s, bool doStore) {
        // ---- projection of PREVIOUS h: independent of hq/dot, fills the
        // lgkm wait and dot-issue phase ----
        if (doStore) {
            const float pr = half_sum32(h * wout);
            if ((l & 31) == 31) out[outPr] = pr + bout;
            outPr += B_;
        }
        // x broadcast: register readlane (h-independent)
        const int xr0 = __builtin_amdgcn_readlane(__builtin_bit_cast(int, xcur), s);
        const int xr1 = __builtin_amdgcn_readlane(__builtin_bit_cast(int, xcur), s + 32);
        const float xk = p ? __builtin_bit_cast(float, xr1)
                           : __builtin_bit_cast(float, xr0);
        // dot accumulators start at the x-term
        v2f ai0 = {bi  + xk * wxi, 0.f}, ai1 = {0.f, 0.f};
        v2f af0 = {bf  + xk * wxf, 0.f}, af1 = {0.f, 0.f};
        v2f ag0 = {bg  + xk * wxg, 0.f}, ag1 = {0.f, 0.f};
        v2f ao0 = {bo_ + xk * wxo, 0.f}, ao1 = {0.f, 0.f};
#pragma unroll
        for (int q = 0; q < H_/4; ++q) {
            const v2f hlo = (v2f){ hq[q].x, hq[q].y };
            const v2f hhi = (v2f){ hq[q].z, hq[q].w };
            ai0 += wi[2*q] * hlo;  ai1 += wi[2*q+1] * hhi;
            af0 += wf[2*q] * hlo;  af1 += wf[2*q+1] * hhi;
            ag0 += wg[2*q] * hlo;  ag1 += wg[2*q+1] * hhi;
            ao0 += wo[2*q] * hlo;  ao1 += wo[2*q+1] * hhi;
        }
        const v2f ai = ai0 + ai1, af = af0 + af1;
        const v2f ag = ag0 + ag1, ao = ao0 + ao1;
        const float iv = rcp_(1.0f + ex2_(ai.x + ai.y));
        const float fv = rcp_(1.0f + ex2_(af.x + af.y));
        // gv pre-scaled by 2*L2E: gv2 = 2L2E - 4L2E * rcp(1+exp2(aG))
        const float gv2 = 2.0f*L2E - 4.0f*L2E * rcp_(1.0f + ex2_(ag.x + ag.y));
        const float ov = rcp_(1.0f + ex2_(ao.x + ao.y));
        c2 = fv * c2 + iv * gv2;                       // c2 = 2L2E * c
        const float tc = 1.0f - 2.0f * rcp_(1.0f + ex2_(c2));  // tanh(c)
        h = ov * tc;
        hbuf[wv][p][j] = h;           // publish h_t
        __asm__ __volatile__("" ::: "memory");
        // issue NEXT step's h reads immediately
#pragma unroll
        for (int q = 0; q < H_/4; ++q)
            hq[q] = ((const v4f*)&hbuf[wv][p][0])[q];
    };

    { // chunk 0: peel s=0 (no previous h to project)
        const float xnext = x[(CHUNK + j) * B_ + e];
        body(0, false);
#pragma unroll 8
        for (int s = 1; s < CHUNK; ++s) body(s, true);
        xcur = xnext;
    }
    for (int ch = 1; ch < NCH; ++ch) {
        float xnext = 0.0f;
        if (ch + 1 < NCH) xnext = x[((ch + 1) * CHUNK + j) * B_ + e];
#pragma unroll 8
        for (int s = 0; s < CHUNK; ++s) body(s, true);
        xcur = xnext;
    }
    // final projection: h_{T-1}
    {
        const float pr = half_sum32(h * wout);
        if ((l & 31) == 31) out[outPr] = pr + bout;
    }
    // Final states: hT [1,B,H] then cT [1,B,H] — valid on every lane.
    out[OUTS + e * H_ + j] = h;
    out[OUTS + B_ * H_ + e * H_ + j] = c2 * (0.5f / L2E);
}

extern "C" void kernel_launch(void* const* d_in, const int* in_sizes, int n_in,
                              void* d_out, int out_size, void* d_ws, size_t ws_size,
                              hipStream_t stream) {
    const float* x     = (const float*)d_in[0];
    const float* W_ih  = (const float*)d_in[1];
    const float* W_hh  = (const float*)d_in[2];
    const float* b_ih  = (const float*)d_in[3];
    const float* b_hh  = (const float*)d_in[4];
    const float* W_out = (const float*)d_in[5];
    const float* b_out = (const float*)d_in[6];
    lstm_fused11<<<dim3(B_ / EPB), dim3(256), 0, stream>>>(
        x, W_ih, W_hh, b_ih, b_hh, W_out, b_out, (float*)d_out);
}